// Round 1
// baseline (423.853 us; speedup 1.0000x reference)
//
#include <hip/hip_runtime.h>
#include <hip/hip_bf16.h>
#include <cstdint>

// ---------------- workspace layout (bytes) ----------------
static constexpr size_t OFF_XT   = 0;                                   // bf16 xT [b][y][x][c]  2*4096*1024*2
static constexpr size_t OFF_HIAL = 16777216;                            // f32 hi_al [b][c][hw]  2*1024*4096*4
static constexpr size_t OFF_PART = OFF_HIAL + 33554432;                 // f32 part [16][b][27][4096]
static constexpr size_t OFF_MW   = OFF_PART + 16ull*2*27*4096*4;        // float4 meta weights [b][9][4096]
static constexpr size_t OFF_MI   = OFF_MW  + 2ull*9*4096*16;            // int4 meta indices
static constexpr size_t OFF_WTO  = OFF_MI  + 2ull*9*4096*16;            // f32 wTo [1024][9][28]
static constexpr size_t OFF_WT   = OFF_WTO + 1024ull*252*4;             // f32 wT [32][288][32]
// end = OFF_WT + 32*288*32*4 ~= 69 MB

__device__ __forceinline__ uint16_t f2bf(float f) {
    union { float f; uint32_t u; } x; x.f = f;
    uint32_t u = x.u;
    uint32_t r = (u + 0x7fffu + ((u >> 16) & 1u)) >> 16;   // RNE
    return (uint16_t)r;
}
__device__ __forceinline__ float b2f(uint32_t lo16) {
    union { uint32_t u; float f; } x; x.u = lo16 << 16; return x.f;
}

// ---------------- prep: weight transposes ----------------
__global__ void k_prep_wto(const float* __restrict__ w_off, float* __restrict__ wto) {
    int idx = blockIdx.x * 256 + threadIdx.x;              // 1024*252
    if (idx >= 1024 * 252) return;
    int c = idx / 252, r = idx % 252, p = r / 28, oc = r % 28;
    wto[idx] = (oc < 27) ? w_off[oc * 9216 + c * 9 + p] : 0.f;
}

__global__ void k_prep_wt(const float* __restrict__ w_dcn, float* __restrict__ wt) {
    int idx = blockIdx.x * 256 + threadIdx.x;              // 32*288*32
    if (idx >= 32 * 288 * 32) return;
    int g = idx / 9216, r = idx % 9216, k = r / 32, o = r % 32, i = k / 9, p = k % 9;
    wt[idx] = w_dcn[((g * 32 + o) * 32 + i) * 9 + p];
}

// ---------------- K0: hi_res NCHW f32 -> NHWC bf16 (packed pairs) ----------------
__global__ void k_transpose(const float* __restrict__ x, uint32_t* __restrict__ xt) {
    __shared__ float tile[64][65];
    int cblk = blockIdx.x * 64, y = blockIdx.y, b = blockIdx.z, t = threadIdx.x;
    const float* src = x + ((size_t)(b * 1024 + cblk)) * 4096 + y * 64;
#pragma unroll
    for (int k = 0; k < 16; ++k) {
        int lin = t + k * 256;                 // 4096 = 64c * 64x
        int cl = lin >> 6, xx = lin & 63;
        tile[cl][xx] = src[(size_t)cl * 4096 + xx];
    }
    __syncthreads();
    uint32_t* dst = xt + ((size_t)b * 4096 + y * 64) * 512 + (cblk >> 1);
#pragma unroll
    for (int k = 0; k < 8; ++k) {
        int lin = t + k * 256;                 // 2048 = 64x * 32 cpairs
        int xx = lin >> 5, cp = lin & 31;
        uint32_t lo = f2bf(tile[2 * cp][xx]);
        uint32_t hi = f2bf(tile[2 * cp + 1][xx]);
        dst[(size_t)xx * 512 + cp] = lo | (hi << 16);
    }
}

// ---------------- K1: offset conv 1024->27, K-split x16, partials ----------------
__global__ __launch_bounds__(256) void k_offconv(const float* __restrict__ x,
                                                 const float* __restrict__ wto,
                                                 float* __restrict__ part) {
    int kc = blockIdx.x, rb = blockIdx.y, b = blockIdx.z, t = threadIdx.x;
    int h = rb * 4 + (t >> 6), w = t & 63;
    float4 acc[7];
#pragma unroll
    for (int j = 0; j < 7; ++j) acc[j] = float4{0.f, 0.f, 0.f, 0.f};
    const float* xb = x + (size_t)b * 1024 * 4096;
    for (int c = kc * 64; c < kc * 64 + 64; ++c) {
        const float* xr = xb + (size_t)c * 4096;
        float x9[9];
#pragma unroll
        for (int r = 0; r < 3; ++r) {
            int y = h - 1 + r;
            bool yok = (y >= 0) && (y < 64);
#pragma unroll
            for (int kx = 0; kx < 3; ++kx) {
                int xx = w - 1 + kx;
                x9[r * 3 + kx] = (yok && xx >= 0 && xx < 64) ? xr[y * 64 + xx] : 0.f;
            }
        }
        const float4* wp = (const float4*)(wto + (size_t)c * 252);
#pragma unroll
        for (int p = 0; p < 9; ++p) {
            float xv = x9[p];
#pragma unroll
            for (int ob = 0; ob < 7; ++ob) {
                float4 wv = wp[p * 7 + ob];
                acc[ob].x += xv * wv.x; acc[ob].y += xv * wv.y;
                acc[ob].z += xv * wv.z; acc[ob].w += xv * wv.w;
            }
        }
    }
    float* pb = part + ((size_t)(kc * 2 + b)) * 27 * 4096 + h * 64 + w;
#pragma unroll
    for (int ob = 0; ob < 7; ++ob) {
        int oc = ob * 4;
        if (oc     < 27) pb[(size_t)(oc    ) * 4096] = acc[ob].x;
        if (oc + 1 < 27) pb[(size_t)(oc + 1) * 4096] = acc[ob].y;
        if (oc + 2 < 27) pb[(size_t)(oc + 2) * 4096] = acc[ob].z;
        if (oc + 3 < 27) pb[(size_t)(oc + 3) * 4096] = acc[ob].w;
    }
}

// ---------------- K2: reduce partials -> sampling meta ----------------
__global__ void k_meta(const float* __restrict__ part, const float* __restrict__ b_off,
                       float4* __restrict__ mw, int4* __restrict__ mi) {
    int idx = blockIdx.x * 256 + threadIdx.x;              // 2*9*4096
    if (idx >= 2 * 9 * 4096) return;
    int b = idx / (9 * 4096), r = idx % (9 * 4096), p = r / 4096, hw = r % 4096;
    int h = hw >> 6, w = hw & 63;
    float sdy = b_off[p], sdx = b_off[p + 9], sm = b_off[p + 18];
    for (int k = 0; k < 16; ++k) {
        const float* pb = part + ((size_t)(k * 2 + b)) * 27 * 4096 + hw;
        sdy += pb[(size_t)p * 4096];
        sdx += pb[(size_t)(p + 9) * 4096];
        sm  += pb[(size_t)(p + 18) * 4096];
    }
    float m = 1.f / (1.f + expf(-sm));
    int ky = p / 3 - 1, kx = p % 3 - 1;
    float sy = (float)(h + ky) + sdy;
    float sx = (float)(w + kx) + sdx;
    float y0f = floorf(sy), x0f = floorf(sx);
    float wy = sy - y0f, wx = sx - x0f;
    int y0 = (int)fminf(fmaxf(y0f, -2.f), 64.f);
    int x0 = (int)fminf(fmaxf(x0f, -2.f), 64.f);
    bool vy0 = (y0 >= 0) && (y0 < 64), vy1 = (y0 + 1 >= 0) && (y0 + 1 < 64);
    bool vx0 = (x0 >= 0) && (x0 < 64), vx1 = (x0 + 1 >= 0) && (x0 + 1 < 64);
    float w00 = (1.f - wy) * (1.f - wx) * m * ((vy0 && vx0) ? 1.f : 0.f);
    float w01 = (1.f - wy) * wx         * m * ((vy0 && vx1) ? 1.f : 0.f);
    float w10 = wy * (1.f - wx)         * m * ((vy1 && vx0) ? 1.f : 0.f);
    float w11 = wy * wx                 * m * ((vy1 && vx1) ? 1.f : 0.f);
    int cy0 = min(max(y0, 0), 63),     cx0 = min(max(x0, 0), 63);
    int cy1 = min(max(y0 + 1, 0), 63), cx1 = min(max(x0 + 1, 0), 63);
    mw[idx] = float4{w00, w01, w10, w11};
    mi[idx] = int4{cy0 * 64 + cx0, cy0 * 64 + cx1, cy1 * 64 + cx0, cy1 * 64 + cx1};
}

// ---------------- K3: deformable sample + grouped conv (K=288) ----------------
__global__ __launch_bounds__(256) void k_dcn(const uint32_t* __restrict__ xt,
                                             const float* __restrict__ wt,
                                             const float4* __restrict__ mw,
                                             const int4* __restrict__ mi,
                                             const float* __restrict__ b_dcn,
                                             float* __restrict__ hial) {
    int g = blockIdx.x, h4 = blockIdx.y, b = blockIdx.z, t = threadIdx.x;
    int h = h4 * 4 + (t >> 6), w = t & 63;
    int hw = h * 64 + w;
    float4 acc[8];
#pragma unroll
    for (int j = 0; j < 8; ++j) acc[j] = float4{0.f, 0.f, 0.f, 0.f};
    const uint32_t* xb = xt + (size_t)b * 4096 * 512 + g * 16;
    const float4* wg = (const float4*)(wt + (size_t)g * 9216);
#pragma unroll
    for (int p = 0; p < 9; ++p) {
        int midx = (b * 9 + p) * 4096 + hw;
        float4 wv = mw[midx];
        int4 ix = mi[midx];
        const uint32_t* p00 = xb + (size_t)ix.x * 512;
        const uint32_t* p01 = xb + (size_t)ix.y * 512;
        const uint32_t* p10 = xb + (size_t)ix.z * 512;
        const uint32_t* p11 = xb + (size_t)ix.w * 512;
#pragma unroll
        for (int i2 = 0; i2 < 16; ++i2) {
            uint32_t a = p00[i2], cc = p01[i2], d = p10[i2], e = p11[i2];
            float v0 = wv.x * b2f(a & 0xffffu) + wv.y * b2f(cc & 0xffffu)
                     + wv.z * b2f(d & 0xffffu) + wv.w * b2f(e & 0xffffu);
            float v1 = wv.x * b2f(a >> 16) + wv.y * b2f(cc >> 16)
                     + wv.z * b2f(d >> 16) + wv.w * b2f(e >> 16);
            const float4* w0p = wg + ((size_t)((2 * i2) * 9 + p)) * 8;
            const float4* w1p = wg + ((size_t)((2 * i2 + 1) * 9 + p)) * 8;
#pragma unroll
            for (int ob = 0; ob < 8; ++ob) {
                float4 wa = w0p[ob];
                acc[ob].x += v0 * wa.x; acc[ob].y += v0 * wa.y;
                acc[ob].z += v0 * wa.z; acc[ob].w += v0 * wa.w;
            }
#pragma unroll
            for (int ob = 0; ob < 8; ++ob) {
                float4 wb = w1p[ob];
                acc[ob].x += v1 * wb.x; acc[ob].y += v1 * wb.y;
                acc[ob].z += v1 * wb.z; acc[ob].w += v1 * wb.w;
            }
        }
    }
    const float* bd = b_dcn + g * 32;
    float* ob_ = hial + ((size_t)b * 1024 + g * 32) * 4096 + hw;
#pragma unroll
    for (int j = 0; j < 8; ++j) {
        ob_[(size_t)(j * 4 + 0) * 4096] = acc[j].x + bd[j * 4 + 0];
        ob_[(size_t)(j * 4 + 1) * 4096] = acc[j].y + bd[j * 4 + 1];
        ob_[(size_t)(j * 4 + 2) * 4096] = acc[j].z + bd[j * 4 + 2];
        ob_[(size_t)(j * 4 + 3) * 4096] = acc[j].w + bd[j * 4 + 3];
    }
}

// ---------------- K4: fused bilinear 2x upsample + grouped 1x1 conv ----------------
__global__ __launch_bounds__(256) void k_post(const float* __restrict__ lo,
                                              const float* __restrict__ hial,
                                              const float* __restrict__ wp,
                                              const float* __restrict__ bp,
                                              float* __restrict__ out) {
    int gb = blockIdx.x, h = blockIdx.y, b = blockIdx.z, t = threadIdx.x;
    int w = t & 63, gl = t >> 6;
    int g = gb * 4 + gl;
    float fy = 0.5f * h - 0.25f; float fy0 = floorf(fy); float ty = fy - fy0;
    int r0 = (int)fy0; int r1 = r0 + 1; r0 = r0 < 0 ? 0 : r0; r1 = r1 > 31 ? 31 : r1;
    float fx = 0.5f * w - 0.25f; float fx0 = floorf(fx); float tx = fx - fx0;
    int c0 = (int)fx0; int c1 = c0 + 1; c0 = c0 < 0 ? 0 : c0; c1 = c1 > 31 ? 31 : c1;
    float v[12];
    int cbase = g * 12;
#pragma unroll
    for (int i = 0; i < 12; ++i) {
        int c = cbase + i;
        if (c < 2048) {
            const float* lb = lo + ((size_t)(b * 2048 + c)) * 1024;
            float a00 = lb[r0 * 32 + c0], a01 = lb[r0 * 32 + c1];
            float a10 = lb[r1 * 32 + c0], a11 = lb[r1 * 32 + c1];
            v[i] = (1.f - ty) * ((1.f - tx) * a00 + tx * a01)
                 + ty * ((1.f - tx) * a10 + tx * a11);
        } else {
            v[i] = hial[((size_t)b * 1024 + (c - 2048)) * 4096 + h * 64 + w];
        }
    }
    const float* wrow = wp + (size_t)g * 96;   // 8 o * 12 i
    float* ob_ = out + ((size_t)b * 2048 + g * 8) * 4096 + h * 64 + w;
#pragma unroll
    for (int o = 0; o < 8; ++o) {
        float s = bp[g * 8 + o];
#pragma unroll
        for (int i = 0; i < 12; ++i) s += wrow[o * 12 + i] * v[i];
        ob_[(size_t)o * 4096] = s;
    }
}

extern "C" void kernel_launch(void* const* d_in, const int* in_sizes, int n_in,
                              void* d_out, int out_size, void* d_ws, size_t ws_size,
                              hipStream_t stream) {
    const float* lo_res = (const float*)d_in[0];
    const float* hi_res = (const float*)d_in[1];
    const float* w_off  = (const float*)d_in[2];
    const float* b_off  = (const float*)d_in[3];
    const float* w_dcn  = (const float*)d_in[4];
    const float* b_dcn  = (const float*)d_in[5];
    const float* w_post = (const float*)d_in[6];
    const float* b_post = (const float*)d_in[7];
    float* out = (float*)d_out;
    char* ws = (char*)d_ws;

    uint32_t* xt  = (uint32_t*)(ws + OFF_XT);
    float* hial   = (float*)(ws + OFF_HIAL);
    float* part   = (float*)(ws + OFF_PART);
    float4* mwp   = (float4*)(ws + OFF_MW);
    int4* mip     = (int4*)(ws + OFF_MI);
    float* wto    = (float*)(ws + OFF_WTO);
    float* wt     = (float*)(ws + OFF_WT);

    k_prep_wto<<<(1024 * 252 + 255) / 256, 256, 0, stream>>>(w_off, wto);
    k_prep_wt<<<(32 * 288 * 32 + 255) / 256, 256, 0, stream>>>(w_dcn, wt);
    k_transpose<<<dim3(16, 64, 2), 256, 0, stream>>>(hi_res, xt);
    k_offconv<<<dim3(16, 16, 2), 256, 0, stream>>>(hi_res, wto, part);
    k_meta<<<(2 * 9 * 4096 + 255) / 256, 256, 0, stream>>>(part, b_off, mwp, mip);
    k_dcn<<<dim3(32, 16, 2), 256, 0, stream>>>(xt, wt, mwp, mip, b_dcn, hial);
    k_post<<<dim3(64, 64, 2), 256, 0, stream>>>(lo_res, hial, w_post, b_post, out);
}

// Round 2
// 252.963 us; speedup vs baseline: 1.6756x; 1.6756x over previous
//
#include <hip/hip_runtime.h>
#include <hip/hip_bf16.h>
#include <cstdint>

// ---------------- workspace layout (bytes) ----------------
static constexpr size_t OFF_XT   = 0;                                   // bf16 xT [b][y][x][c]  2*4096*1024*2 = 16 MB
static constexpr size_t OFF_HIAL = 16777216;                            // f32 hi_al [b][c][hw]  2*1024*4096*4 = 32 MB
static constexpr size_t OFF_PART = OFF_HIAL + 33554432;                 // f32 part [9][b][32][4096] = 9.4 MB
static constexpr size_t OFF_MW   = OFF_PART + 9ull*2*32*4096*4;         // float4 meta weights [b][9][4096]
static constexpr size_t OFF_MI   = OFF_MW  + 2ull*9*4096*16;            // int4 meta indices
static constexpr size_t OFF_WA   = OFF_MI  + 2ull*9*4096*16;            // bf16 wA [9][32][1024] (u32-packed)
static constexpr size_t OFF_WT   = OFF_WA  + 9ull*32*512*4;             // f32 wT [32][288][32]
// end = OFF_WT + 32*288*32*4 ~= 64 MB

typedef __attribute__((ext_vector_type(8))) short bf16x8;
typedef __attribute__((ext_vector_type(4))) float f32x4;

__device__ __forceinline__ uint16_t f2bf(float f) {
    union { float f; uint32_t u; } x; x.f = f;
    uint32_t u = x.u;
    uint32_t r = (u + 0x7fffu + ((u >> 16) & 1u)) >> 16;   // RNE
    return (uint16_t)r;
}
__device__ __forceinline__ float b2f(uint32_t lo16) {
    union { uint32_t u; float f; } x; x.u = lo16 << 16; return x.f;
}

// ---------------- prep: weight transposes ----------------
// wa[p][oc(32, pad27)][c(1024)] bf16 packed into u32 pairs: [9][32][512] u32
__global__ void k_prep_wa(const float* __restrict__ w_off, uint32_t* __restrict__ wa) {
    int idx = blockIdx.x * 256 + threadIdx.x;              // 9*32*512
    if (idx >= 9 * 32 * 512) return;
    int p = idx / (32 * 512), r = idx % (32 * 512), oc = r / 512, cp = r % 512;
    uint32_t lo = 0, hi = 0;
    if (oc < 27) {
        lo = f2bf(w_off[(size_t)oc * 9216 + (size_t)(cp * 2) * 9 + p]);
        hi = f2bf(w_off[(size_t)oc * 9216 + (size_t)(cp * 2 + 1) * 9 + p]);
    }
    wa[idx] = lo | (hi << 16);
}

__global__ void k_prep_wt(const float* __restrict__ w_dcn, float* __restrict__ wt) {
    int idx = blockIdx.x * 256 + threadIdx.x;              // 32*288*32
    if (idx >= 32 * 288 * 32) return;
    int g = idx / 9216, r = idx % 9216, k = r / 32, o = r % 32, i = k / 9, p = k % 9;
    wt[idx] = w_dcn[((g * 32 + o) * 32 + i) * 9 + p];
}

// ---------------- K0: hi_res NCHW f32 -> NHWC bf16 (packed pairs) ----------------
__global__ void k_transpose(const float* __restrict__ x, uint32_t* __restrict__ xt) {
    __shared__ float tile[64][65];
    int cblk = blockIdx.x * 64, y = blockIdx.y, b = blockIdx.z, t = threadIdx.x;
    const float* src = x + ((size_t)(b * 1024 + cblk)) * 4096 + y * 64;
#pragma unroll
    for (int k = 0; k < 16; ++k) {
        int lin = t + k * 256;                 // 4096 = 64c * 64x
        int cl = lin >> 6, xx = lin & 63;
        tile[cl][xx] = src[(size_t)cl * 4096 + xx];
    }
    __syncthreads();
    uint32_t* dst = xt + ((size_t)b * 4096 + y * 64) * 512 + (cblk >> 1);
#pragma unroll
    for (int k = 0; k < 8; ++k) {
        int lin = t + k * 256;                 // 2048 = 64x * 32 cpairs
        int xx = lin >> 5, cp = lin & 31;
        uint32_t lo = f2bf(tile[2 * cp][xx]);
        uint32_t hi = f2bf(tile[2 * cp + 1][xx]);
        dst[(size_t)xx * 512 + cp] = lo | (hi << 16);
    }
}

// ---------------- K1: offset conv via MFMA, split by the 9 stencil shifts ----------------
// out_part[p][b][32 oc][4096 hw] = W_p[32 x 1024] x X_shift_p[1024 x 4096]   (bf16 MFMA, f32 acc)
__global__ __launch_bounds__(256) void k_offconv_mfma(const uint32_t* __restrict__ xt,
                                                      const uint32_t* __restrict__ wa,
                                                      float* __restrict__ part) {
    int p = blockIdx.x;                        // shift 0..8
    int y = blockIdx.y;                        // image row 0..63
    int b = blockIdx.z;
    int t = threadIdx.x;
    int wave = t >> 6, lane = t & 63;
    int col = lane & 15, kg = lane >> 4;       // C col / K-chunk per MFMA layout
    int x = wave * 16 + col;                   // pixel x for B operand / C store
    int ky = p / 3 - 1, kx = p % 3 - 1;
    int ys = y + ky, xs = x + kx;
    bool ok = (ys >= 0) && (ys < 64) && (xs >= 0) && (xs < 64);
    int ps = ok ? (ys * 64 + xs) : 0;

    const uint32_t* bp = xt + (size_t)b * 4096 * 512 + (size_t)ps * 512 + kg * 4;
    const uint32_t* a0 = wa + ((size_t)p * 32 + (lane & 15)) * 512 + kg * 4;   // M-tile 0 (oc 0..15)
    const uint32_t* a1 = a0 + 16 * 512;                                        // M-tile 1 (oc 16..31)

    f32x4 acc0 = {0.f, 0.f, 0.f, 0.f};
    f32x4 acc1 = {0.f, 0.f, 0.f, 0.f};
#pragma unroll 4
    for (int ks = 0; ks < 32; ++ks) {
        bf16x8 bfrag = {0, 0, 0, 0, 0, 0, 0, 0};
        if (ok) bfrag = *(const bf16x8*)(bp + ks * 16);
        bf16x8 af0 = *(const bf16x8*)(a0 + ks * 16);
        bf16x8 af1 = *(const bf16x8*)(a1 + ks * 16);
        acc0 = __builtin_amdgcn_mfma_f32_16x16x32_bf16(af0, bfrag, acc0, 0, 0, 0);
        acc1 = __builtin_amdgcn_mfma_f32_16x16x32_bf16(af1, bfrag, acc1, 0, 0, 0);
    }
    // C layout: col = lane&15 (pixel), row = kg*4 + j (oc within tile)
    float* pc = part + ((size_t)(p * 2 + b)) * 32 * 4096 + (size_t)y * 64 + wave * 16 + col;
#pragma unroll
    for (int j = 0; j < 4; ++j) {
        pc[(size_t)(kg * 4 + j) * 4096]      = acc0[j];
        pc[(size_t)(16 + kg * 4 + j) * 4096] = acc1[j];
    }
}

// ---------------- K2: reduce shift-partials -> sampling meta ----------------
__global__ void k_meta(const float* __restrict__ part, const float* __restrict__ b_off,
                       float4* __restrict__ mw, int4* __restrict__ mi) {
    int idx = blockIdx.x * 256 + threadIdx.x;              // 2*9*4096
    if (idx >= 2 * 9 * 4096) return;
    int b = idx / (9 * 4096), r = idx % (9 * 4096), p = r / 4096, hw = r % 4096;
    int h = hw >> 6, w = hw & 63;
    float sdy = b_off[p], sdx = b_off[p + 9], sm = b_off[p + 18];
#pragma unroll
    for (int s = 0; s < 9; ++s) {
        const float* pb = part + ((size_t)(s * 2 + b)) * 32 * 4096 + hw;
        sdy += pb[(size_t)p * 4096];
        sdx += pb[(size_t)(p + 9) * 4096];
        sm  += pb[(size_t)(p + 18) * 4096];
    }
    float m = 1.f / (1.f + expf(-sm));
    int ky = p / 3 - 1, kx = p % 3 - 1;
    float sy = (float)(h + ky) + sdy;
    float sx = (float)(w + kx) + sdx;
    float y0f = floorf(sy), x0f = floorf(sx);
    float wy = sy - y0f, wx = sx - x0f;
    int y0 = (int)fminf(fmaxf(y0f, -2.f), 64.f);
    int x0 = (int)fminf(fmaxf(x0f, -2.f), 64.f);
    bool vy0 = (y0 >= 0) && (y0 < 64), vy1 = (y0 + 1 >= 0) && (y0 + 1 < 64);
    bool vx0 = (x0 >= 0) && (x0 < 64), vx1 = (x0 + 1 >= 0) && (x0 + 1 < 64);
    float w00 = (1.f - wy) * (1.f - wx) * m * ((vy0 && vx0) ? 1.f : 0.f);
    float w01 = (1.f - wy) * wx         * m * ((vy0 && vx1) ? 1.f : 0.f);
    float w10 = wy * (1.f - wx)         * m * ((vy1 && vx0) ? 1.f : 0.f);
    float w11 = wy * wx                 * m * ((vy1 && vx1) ? 1.f : 0.f);
    int cy0 = min(max(y0, 0), 63),     cx0 = min(max(x0, 0), 63);
    int cy1 = min(max(y0 + 1, 0), 63), cx1 = min(max(x0 + 1, 0), 63);
    mw[idx] = float4{w00, w01, w10, w11};
    mi[idx] = int4{cy0 * 64 + cx0, cy0 * 64 + cx1, cy1 * 64 + cx0, cy1 * 64 + cx1};
}

// ---------------- K3: deformable sample + grouped conv (K=288) ----------------
__global__ __launch_bounds__(256) void k_dcn(const uint32_t* __restrict__ xt,
                                             const float* __restrict__ wt,
                                             const float4* __restrict__ mw,
                                             const int4* __restrict__ mi,
                                             const float* __restrict__ b_dcn,
                                             float* __restrict__ hial) {
    int g = blockIdx.x, h4 = blockIdx.y, b = blockIdx.z, t = threadIdx.x;
    int h = h4 * 4 + (t >> 6), w = t & 63;
    int hw = h * 64 + w;
    float4 acc[8];
#pragma unroll
    for (int j = 0; j < 8; ++j) acc[j] = float4{0.f, 0.f, 0.f, 0.f};
    const uint32_t* xb = xt + (size_t)b * 4096 * 512 + g * 16;
    const float4* wg = (const float4*)(wt + (size_t)g * 9216);
#pragma unroll
    for (int p = 0; p < 9; ++p) {
        int midx = (b * 9 + p) * 4096 + hw;
        float4 wv = mw[midx];
        int4 ix = mi[midx];
        const uint32_t* p00 = xb + (size_t)ix.x * 512;
        const uint32_t* p01 = xb + (size_t)ix.y * 512;
        const uint32_t* p10 = xb + (size_t)ix.z * 512;
        const uint32_t* p11 = xb + (size_t)ix.w * 512;
#pragma unroll
        for (int i2 = 0; i2 < 16; ++i2) {
            uint32_t a = p00[i2], cc = p01[i2], d = p10[i2], e = p11[i2];
            float v0 = wv.x * b2f(a & 0xffffu) + wv.y * b2f(cc & 0xffffu)
                     + wv.z * b2f(d & 0xffffu) + wv.w * b2f(e & 0xffffu);
            float v1 = wv.x * b2f(a >> 16) + wv.y * b2f(cc >> 16)
                     + wv.z * b2f(d >> 16) + wv.w * b2f(e >> 16);
            const float4* w0p = wg + ((size_t)((2 * i2) * 9 + p)) * 8;
            const float4* w1p = wg + ((size_t)((2 * i2 + 1) * 9 + p)) * 8;
#pragma unroll
            for (int ob = 0; ob < 8; ++ob) {
                float4 wa = w0p[ob];
                acc[ob].x += v0 * wa.x; acc[ob].y += v0 * wa.y;
                acc[ob].z += v0 * wa.z; acc[ob].w += v0 * wa.w;
            }
#pragma unroll
            for (int ob = 0; ob < 8; ++ob) {
                float4 wb = w1p[ob];
                acc[ob].x += v1 * wb.x; acc[ob].y += v1 * wb.y;
                acc[ob].z += v1 * wb.z; acc[ob].w += v1 * wb.w;
            }
        }
    }
    const float* bd = b_dcn + g * 32;
    float* ob_ = hial + ((size_t)b * 1024 + g * 32) * 4096 + hw;
#pragma unroll
    for (int j = 0; j < 8; ++j) {
        ob_[(size_t)(j * 4 + 0) * 4096] = acc[j].x + bd[j * 4 + 0];
        ob_[(size_t)(j * 4 + 1) * 4096] = acc[j].y + bd[j * 4 + 1];
        ob_[(size_t)(j * 4 + 2) * 4096] = acc[j].z + bd[j * 4 + 2];
        ob_[(size_t)(j * 4 + 3) * 4096] = acc[j].w + bd[j * 4 + 3];
    }
}

// ---------------- K4: fused bilinear 2x upsample + grouped 1x1 conv ----------------
__global__ __launch_bounds__(256) void k_post(const float* __restrict__ lo,
                                              const float* __restrict__ hial,
                                              const float* __restrict__ wp,
                                              const float* __restrict__ bp,
                                              float* __restrict__ out) {
    int gb = blockIdx.x, h = blockIdx.y, b = blockIdx.z, t = threadIdx.x;
    int w = t & 63, gl = t >> 6;
    int g = gb * 4 + gl;
    float fy = 0.5f * h - 0.25f; float fy0 = floorf(fy); float ty = fy - fy0;
    int r0 = (int)fy0; int r1 = r0 + 1; r0 = r0 < 0 ? 0 : r0; r1 = r1 > 31 ? 31 : r1;
    float fx = 0.5f * w - 0.25f; float fx0 = floorf(fx); float tx = fx - fx0;
    int c0 = (int)fx0; int c1 = c0 + 1; c0 = c0 < 0 ? 0 : c0; c1 = c1 > 31 ? 31 : c1;
    float v[12];
    int cbase = g * 12;
#pragma unroll
    for (int i = 0; i < 12; ++i) {
        int c = cbase + i;
        if (c < 2048) {
            const float* lb = lo + ((size_t)(b * 2048 + c)) * 1024;
            float a00 = lb[r0 * 32 + c0], a01 = lb[r0 * 32 + c1];
            float a10 = lb[r1 * 32 + c0], a11 = lb[r1 * 32 + c1];
            v[i] = (1.f - ty) * ((1.f - tx) * a00 + tx * a01)
                 + ty * ((1.f - tx) * a10 + tx * a11);
        } else {
            v[i] = hial[((size_t)b * 1024 + (c - 2048)) * 4096 + h * 64 + w];
        }
    }
    const float* wrow = wp + (size_t)g * 96;   // 8 o * 12 i
    float* ob_ = out + ((size_t)b * 2048 + g * 8) * 4096 + h * 64 + w;
#pragma unroll
    for (int o = 0; o < 8; ++o) {
        float s = bp[g * 8 + o];
#pragma unroll
        for (int i = 0; i < 12; ++i) s += wrow[o * 12 + i] * v[i];
        ob_[(size_t)o * 4096] = s;
    }
}

extern "C" void kernel_launch(void* const* d_in, const int* in_sizes, int n_in,
                              void* d_out, int out_size, void* d_ws, size_t ws_size,
                              hipStream_t stream) {
    const float* lo_res = (const float*)d_in[0];
    const float* hi_res = (const float*)d_in[1];
    const float* w_off  = (const float*)d_in[2];
    const float* b_off  = (const float*)d_in[3];
    const float* w_dcn  = (const float*)d_in[4];
    const float* b_dcn  = (const float*)d_in[5];
    const float* w_post = (const float*)d_in[6];
    const float* b_post = (const float*)d_in[7];
    float* out = (float*)d_out;
    char* ws = (char*)d_ws;

    uint32_t* xt  = (uint32_t*)(ws + OFF_XT);
    float* hial   = (float*)(ws + OFF_HIAL);
    float* part   = (float*)(ws + OFF_PART);
    float4* mwp   = (float4*)(ws + OFF_MW);
    int4* mip     = (int4*)(ws + OFF_MI);
    uint32_t* wa  = (uint32_t*)(ws + OFF_WA);
    float* wt     = (float*)(ws + OFF_WT);

    k_prep_wa<<<(9 * 32 * 512 + 255) / 256, 256, 0, stream>>>(w_off, wa);
    k_prep_wt<<<(32 * 288 * 32 + 255) / 256, 256, 0, stream>>>(w_dcn, wt);
    k_transpose<<<dim3(16, 64, 2), 256, 0, stream>>>(hi_res, xt);
    k_offconv_mfma<<<dim3(9, 64, 2), 256, 0, stream>>>(xt, wa, part);
    k_meta<<<(2 * 9 * 4096 + 255) / 256, 256, 0, stream>>>(part, b_off, mwp, mip);
    k_dcn<<<dim3(32, 16, 2), 256, 0, stream>>>(xt, wt, mwp, mip, b_dcn, hial);
    k_post<<<dim3(64, 64, 2), 256, 0, stream>>>(lo_res, hial, w_post, b_post, out);
}

// Round 3
// 211.160 us; speedup vs baseline: 2.0073x; 1.1980x over previous
//
#include <hip/hip_runtime.h>
#include <hip/hip_bf16.h>
#include <cstdint>

// ---------------- workspace layout (bytes) ----------------
static constexpr size_t OFF_XT   = 0;                                   // bf16 xT [b][hw][c] packed u32 pairs, 16 MB
static constexpr size_t OFF_HIAL = 16777216;                            // f32 hi_al [b][c][hw] 32 MB
static constexpr size_t OFF_PART = OFF_HIAL + 33554432;                 // f32 part [9][b][32][4096] = 9.4 MB
static constexpr size_t OFF_MW   = OFF_PART + 9ull*2*32*4096*4;         // float4 meta weights [b][9][4096]
static constexpr size_t OFF_MI   = OFF_MW  + 2ull*9*4096*16;            // int4 meta indices
static constexpr size_t OFF_WA   = OFF_MI  + 2ull*9*4096*16;            // bf16 wA [9][32oc][1024c] u32-packed (offconv)
static constexpr size_t OFF_WB   = OFF_WA  + 9ull*32*512*4;             // bf16 wB [32g][9p][32o][32i] u32-packed (dcn)
// end ~= 63.3 MB

typedef __attribute__((ext_vector_type(8))) short bf16x8;
typedef __attribute__((ext_vector_type(4))) float f32x4;

__device__ __forceinline__ uint16_t f2bf(float f) {
    union { float f; uint32_t u; } x; x.f = f;
    uint32_t u = x.u;
    uint32_t r = (u + 0x7fffu + ((u >> 16) & 1u)) >> 16;   // RNE
    return (uint16_t)r;
}
__device__ __forceinline__ float b2f_lo(uint32_t v) {
    union { uint32_t u; float f; } x; x.u = v << 16; return x.f;
}
__device__ __forceinline__ float b2f_hi(uint32_t v) {
    union { uint32_t u; float f; } x; x.u = v & 0xffff0000u; return x.f;
}
// pack two f32 -> one u32 of two bf16 (round-half-up, cheap)
__device__ __forceinline__ uint32_t pk_bf(float lo, float hi) {
    union { float f; uint32_t u; } a, b; a.f = lo; b.f = hi;
    return ((a.u + 0x8000u) >> 16) | ((b.u + 0x8000u) & 0xffff0000u);
}

// ---------------- prep: weight transposes ----------------
// wa[p][oc(32, pad27)][c(1024)] bf16 packed into u32 pairs: [9][32][512] u32
__global__ void k_prep_wa(const float* __restrict__ w_off, uint32_t* __restrict__ wa) {
    int idx = blockIdx.x * 256 + threadIdx.x;              // 9*32*512
    if (idx >= 9 * 32 * 512) return;
    int p = idx / (32 * 512), r = idx % (32 * 512), oc = r / 512, cp = r % 512;
    uint32_t lo = 0, hi = 0;
    if (oc < 27) {
        lo = f2bf(w_off[(size_t)oc * 9216 + (size_t)(cp * 2) * 9 + p]);
        hi = f2bf(w_off[(size_t)oc * 9216 + (size_t)(cp * 2 + 1) * 9 + p]);
    }
    wa[idx] = lo | (hi << 16);
}

// wb[g][p][o][i] bf16 packed: [32][9][32][16] u32
__global__ void k_prep_wb(const float* __restrict__ w_dcn, uint32_t* __restrict__ wb) {
    int idx = blockIdx.x * 256 + threadIdx.x;              // 32*9*32*16
    if (idx >= 32 * 9 * 32 * 16) return;
    int g = idx / (9 * 32 * 16), r = idx % (9 * 32 * 16);
    int p = r / (32 * 16), r2 = r % (32 * 16), o = r2 / 16, ip = r2 % 16;
    uint32_t lo = f2bf(w_dcn[((size_t)(g * 32 + o) * 32 + 2 * ip) * 9 + p]);
    uint32_t hi = f2bf(w_dcn[((size_t)(g * 32 + o) * 32 + 2 * ip + 1) * 9 + p]);
    wb[idx] = lo | (hi << 16);
}

// ---------------- K0: hi_res NCHW f32 -> NHWC bf16 (packed pairs) ----------------
__global__ void k_transpose(const float* __restrict__ x, uint32_t* __restrict__ xt) {
    __shared__ float tile[64][65];
    int cblk = blockIdx.x * 64, y = blockIdx.y, b = blockIdx.z, t = threadIdx.x;
    const float* src = x + ((size_t)(b * 1024 + cblk)) * 4096 + y * 64;
#pragma unroll
    for (int k = 0; k < 16; ++k) {
        int lin = t + k * 256;                 // 4096 = 64c * 64x
        int cl = lin >> 6, xx = lin & 63;
        tile[cl][xx] = src[(size_t)cl * 4096 + xx];
    }
    __syncthreads();
    uint32_t* dst = xt + ((size_t)b * 4096 + y * 64) * 512 + (cblk >> 1);
#pragma unroll
    for (int k = 0; k < 8; ++k) {
        int lin = t + k * 256;                 // 2048 = 64x * 32 cpairs
        int xx = lin >> 5, cp = lin & 31;
        uint32_t lo = f2bf(tile[2 * cp][xx]);
        uint32_t hi = f2bf(tile[2 * cp + 1][xx]);
        dst[(size_t)xx * 512 + cp] = lo | (hi << 16);
    }
}

// ---------------- K1: offset conv via MFMA, split by the 9 stencil shifts ----------------
__global__ __launch_bounds__(256) void k_offconv_mfma(const uint32_t* __restrict__ xt,
                                                      const uint32_t* __restrict__ wa,
                                                      float* __restrict__ part) {
    int p = blockIdx.x;                        // shift 0..8
    int y = blockIdx.y;                        // image row 0..63
    int b = blockIdx.z;
    int t = threadIdx.x;
    int wave = t >> 6, lane = t & 63;
    int col = lane & 15, kg = lane >> 4;
    int x = wave * 16 + col;
    int ky = p / 3 - 1, kx = p % 3 - 1;
    int ys = y + ky, xs = x + kx;
    bool ok = (ys >= 0) && (ys < 64) && (xs >= 0) && (xs < 64);
    int ps = ok ? (ys * 64 + xs) : 0;

    const uint32_t* bp = xt + (size_t)b * 4096 * 512 + (size_t)ps * 512 + kg * 4;
    const uint32_t* a0 = wa + ((size_t)p * 32 + col) * 512 + kg * 4;
    const uint32_t* a1 = a0 + 16 * 512;

    f32x4 acc0 = {0.f, 0.f, 0.f, 0.f};
    f32x4 acc1 = {0.f, 0.f, 0.f, 0.f};
#pragma unroll 4
    for (int ks = 0; ks < 32; ++ks) {
        bf16x8 bfrag = {0, 0, 0, 0, 0, 0, 0, 0};
        if (ok) bfrag = *(const bf16x8*)(bp + ks * 16);
        bf16x8 af0 = *(const bf16x8*)(a0 + ks * 16);
        bf16x8 af1 = *(const bf16x8*)(a1 + ks * 16);
        acc0 = __builtin_amdgcn_mfma_f32_16x16x32_bf16(af0, bfrag, acc0, 0, 0, 0);
        acc1 = __builtin_amdgcn_mfma_f32_16x16x32_bf16(af1, bfrag, acc1, 0, 0, 0);
    }
    float* pc = part + ((size_t)(p * 2 + b)) * 32 * 4096 + (size_t)y * 64 + wave * 16 + col;
#pragma unroll
    for (int j = 0; j < 4; ++j) {
        pc[(size_t)(kg * 4 + j) * 4096]      = acc0[j];
        pc[(size_t)(16 + kg * 4 + j) * 4096] = acc1[j];
    }
}

// ---------------- K2: reduce shift-partials -> sampling meta ----------------
__global__ void k_meta(const float* __restrict__ part, const float* __restrict__ b_off,
                       float4* __restrict__ mw, int4* __restrict__ mi) {
    int idx = blockIdx.x * 256 + threadIdx.x;              // 2*9*4096
    if (idx >= 2 * 9 * 4096) return;
    int b = idx / (9 * 4096), r = idx % (9 * 4096), p = r / 4096, hw = r % 4096;
    int h = hw >> 6, w = hw & 63;
    float sdy = b_off[p], sdx = b_off[p + 9], sm = b_off[p + 18];
#pragma unroll
    for (int s = 0; s < 9; ++s) {
        const float* pb = part + ((size_t)(s * 2 + b)) * 32 * 4096 + hw;
        sdy += pb[(size_t)p * 4096];
        sdx += pb[(size_t)(p + 9) * 4096];
        sm  += pb[(size_t)(p + 18) * 4096];
    }
    float m = 1.f / (1.f + expf(-sm));
    int ky = p / 3 - 1, kx = p % 3 - 1;
    float sy = (float)(h + ky) + sdy;
    float sx = (float)(w + kx) + sdx;
    float y0f = floorf(sy), x0f = floorf(sx);
    float wy = sy - y0f, wx = sx - x0f;
    int y0 = (int)fminf(fmaxf(y0f, -2.f), 64.f);
    int x0 = (int)fminf(fmaxf(x0f, -2.f), 64.f);
    bool vy0 = (y0 >= 0) && (y0 < 64), vy1 = (y0 + 1 >= 0) && (y0 + 1 < 64);
    bool vx0 = (x0 >= 0) && (x0 < 64), vx1 = (x0 + 1 >= 0) && (x0 + 1 < 64);
    float w00 = (1.f - wy) * (1.f - wx) * m * ((vy0 && vx0) ? 1.f : 0.f);
    float w01 = (1.f - wy) * wx         * m * ((vy0 && vx1) ? 1.f : 0.f);
    float w10 = wy * (1.f - wx)         * m * ((vy1 && vx0) ? 1.f : 0.f);
    float w11 = wy * wx                 * m * ((vy1 && vx1) ? 1.f : 0.f);
    int cy0 = min(max(y0, 0), 63),     cx0 = min(max(x0, 0), 63);
    int cy1 = min(max(y0 + 1, 0), 63), cx1 = min(max(x0 + 1, 0), 63);
    mw[idx] = float4{w00, w01, w10, w11};
    mi[idx] = int4{cy0 * 64 + cx0, cy0 * 64 + cx1, cy1 * 64 + cx0, cy1 * 64 + cx1};
}

// ---------------- K3: deformable sample + grouped conv via MFMA ----------------
// per (b,g): out[32 o][4096 hw] = W[32 x 288] x val[288 x hw]; K-step = one tap p (32 channels)
__global__ __launch_bounds__(256) void k_dcn_mfma(const uint32_t* __restrict__ xt,
                                                  const uint32_t* __restrict__ wb,
                                                  const float4* __restrict__ mw,
                                                  const int4* __restrict__ mi,
                                                  const float* __restrict__ b_dcn,
                                                  float* __restrict__ hial) {
    int g = blockIdx.x, y = blockIdx.y, b = blockIdx.z;
    int t = threadIdx.x, wave = t >> 6, lane = t & 63;
    int col = lane & 15, kg = lane >> 4;
    int pix = y * 64 + wave * 16 + col;

    const uint32_t* xb = xt + (size_t)b * 4096 * 512 + g * 16 + kg * 4;
    const uint32_t* wg = wb + (size_t)g * 9 * 32 * 16 + col * 16 + kg * 4;

    f32x4 acc0 = {0.f, 0.f, 0.f, 0.f};
    f32x4 acc1 = {0.f, 0.f, 0.f, 0.f};
#pragma unroll
    for (int p = 0; p < 9; ++p) {
        int midx = (b * 9 + p) * 4096 + pix;
        float4 wv = mw[midx];
        int4 ix = mi[midx];
        uint4 u00 = *(const uint4*)(xb + (size_t)ix.x * 512);
        uint4 u01 = *(const uint4*)(xb + (size_t)ix.y * 512);
        uint4 u10 = *(const uint4*)(xb + (size_t)ix.z * 512);
        uint4 u11 = *(const uint4*)(xb + (size_t)ix.w * 512);
        union { uint32_t u[4]; bf16x8 v; } bfr;
#pragma unroll
        for (int e = 0; e < 4; ++e) {
            uint32_t a = ((const uint32_t*)&u00)[e];
            uint32_t c = ((const uint32_t*)&u01)[e];
            uint32_t d = ((const uint32_t*)&u10)[e];
            uint32_t f = ((const uint32_t*)&u11)[e];
            float lo = wv.x * b2f_lo(a) + wv.y * b2f_lo(c) + wv.z * b2f_lo(d) + wv.w * b2f_lo(f);
            float hi = wv.x * b2f_hi(a) + wv.y * b2f_hi(c) + wv.z * b2f_hi(d) + wv.w * b2f_hi(f);
            bfr.u[e] = pk_bf(lo, hi);
        }
        const uint32_t* ap = wg + (size_t)p * 32 * 16;
        bf16x8 af0 = *(const bf16x8*)ap;
        bf16x8 af1 = *(const bf16x8*)(ap + 16 * 16);
        acc0 = __builtin_amdgcn_mfma_f32_16x16x32_bf16(af0, bfr.v, acc0, 0, 0, 0);
        acc1 = __builtin_amdgcn_mfma_f32_16x16x32_bf16(af1, bfr.v, acc1, 0, 0, 0);
    }
    const float* bd = b_dcn + g * 32;
    float* pc = hial + ((size_t)b * 1024 + g * 32) * 4096 + pix;
#pragma unroll
    for (int j = 0; j < 4; ++j) {
        pc[(size_t)(kg * 4 + j) * 4096]      = acc0[j] + bd[kg * 4 + j];
        pc[(size_t)(16 + kg * 4 + j) * 4096] = acc1[j] + bd[16 + kg * 4 + j];
    }
}

// ---------------- K4: fused bilinear 2x upsample + grouped 1x1 conv ----------------
__global__ __launch_bounds__(256) void k_post(const float* __restrict__ lo,
                                              const float* __restrict__ hial,
                                              const float* __restrict__ wp,
                                              const float* __restrict__ bp,
                                              float* __restrict__ out) {
    int gb = blockIdx.x, h = blockIdx.y, b = blockIdx.z, t = threadIdx.x;
    int w = t & 63, gl = t >> 6;
    int g = gb * 4 + gl;
    float fy = 0.5f * h - 0.25f; float fy0 = floorf(fy); float ty = fy - fy0;
    int r0 = (int)fy0; int r1 = r0 + 1; r0 = r0 < 0 ? 0 : r0; r1 = r1 > 31 ? 31 : r1;
    float fx = 0.5f * w - 0.25f; float fx0 = floorf(fx); float tx = fx - fx0;
    int c0 = (int)fx0; int c1 = c0 + 1; c0 = c0 < 0 ? 0 : c0; c1 = c1 > 31 ? 31 : c1;
    float v[12];
    int cbase = g * 12;
#pragma unroll
    for (int i = 0; i < 12; ++i) {
        int c = cbase + i;
        if (c < 2048) {
            const float* lb = lo + ((size_t)(b * 2048 + c)) * 1024;
            float a00 = lb[r0 * 32 + c0], a01 = lb[r0 * 32 + c1];
            float a10 = lb[r1 * 32 + c0], a11 = lb[r1 * 32 + c1];
            v[i] = (1.f - ty) * ((1.f - tx) * a00 + tx * a01)
                 + ty * ((1.f - tx) * a10 + tx * a11);
        } else {
            v[i] = hial[((size_t)b * 1024 + (c - 2048)) * 4096 + h * 64 + w];
        }
    }
    const float* wrow = wp + (size_t)g * 96;   // 8 o * 12 i
    float* ob_ = out + ((size_t)b * 2048 + g * 8) * 4096 + h * 64 + w;
#pragma unroll
    for (int o = 0; o < 8; ++o) {
        float s = bp[g * 8 + o];
#pragma unroll
        for (int i = 0; i < 12; ++i) s += wrow[o * 12 + i] * v[i];
        ob_[(size_t)o * 4096] = s;
    }
}

extern "C" void kernel_launch(void* const* d_in, const int* in_sizes, int n_in,
                              void* d_out, int out_size, void* d_ws, size_t ws_size,
                              hipStream_t stream) {
    const float* lo_res = (const float*)d_in[0];
    const float* hi_res = (const float*)d_in[1];
    const float* w_off  = (const float*)d_in[2];
    const float* b_off  = (const float*)d_in[3];
    const float* w_dcn  = (const float*)d_in[4];
    const float* b_dcn  = (const float*)d_in[5];
    const float* w_post = (const float*)d_in[6];
    const float* b_post = (const float*)d_in[7];
    float* out = (float*)d_out;
    char* ws = (char*)d_ws;

    uint32_t* xt  = (uint32_t*)(ws + OFF_XT);
    float* hial   = (float*)(ws + OFF_HIAL);
    float* part   = (float*)(ws + OFF_PART);
    float4* mwp   = (float4*)(ws + OFF_MW);
    int4* mip     = (int4*)(ws + OFF_MI);
    uint32_t* wa  = (uint32_t*)(ws + OFF_WA);
    uint32_t* wbp = (uint32_t*)(ws + OFF_WB);

    k_prep_wa<<<(9 * 32 * 512 + 255) / 256, 256, 0, stream>>>(w_off, wa);
    k_prep_wb<<<(32 * 9 * 32 * 16 + 255) / 256, 256, 0, stream>>>(w_dcn, wbp);
    k_transpose<<<dim3(16, 64, 2), 256, 0, stream>>>(hi_res, xt);
    k_offconv_mfma<<<dim3(9, 64, 2), 256, 0, stream>>>(xt, wa, part);
    k_meta<<<(2 * 9 * 4096 + 255) / 256, 256, 0, stream>>>(part, b_off, mwp, mip);
    k_dcn_mfma<<<dim3(32, 64, 2), 256, 0, stream>>>(xt, wbp, mwp, mip, b_dcn, hial);
    k_post<<<dim3(64, 64, 2), 256, 0, stream>>>(lo_res, hial, w_post, b_post, out);
}

// Round 4
// 207.270 us; speedup vs baseline: 2.0449x; 1.0188x over previous
//
#include <hip/hip_runtime.h>
#include <hip/hip_bf16.h>
#include <cstdint>

// ---------------- workspace layout (bytes) ----------------
static constexpr size_t OFF_XT   = 0;                                   // bf16 xT [b][hw][c] packed u32 pairs, 16 MB
static constexpr size_t OFF_HIAL = 16777216;                            // f32 hi_al [b][c][hw] 32 MB
static constexpr size_t OFF_PART = OFF_HIAL;                            // ALIAS: part [18][b][32][4096] f32 (18.9 MB)
                                                                        // safe: k_meta consumes part before k_dcn writes hial
static constexpr size_t OFF_MW   = OFF_HIAL + 33554432;                 // float4 meta weights [b][9][4096]
static constexpr size_t OFF_MI   = OFF_MW  + 2ull*9*4096*16;            // int4 meta indices
static constexpr size_t OFF_WA   = OFF_MI  + 2ull*9*4096*16;            // bf16 wA [9][32oc][1024c] u32-packed (offconv)
static constexpr size_t OFF_WB   = OFF_WA  + 9ull*32*512*4;             // bf16 wB [32g][9p][32o][32i] u32-packed (dcn)
// end ~= 51.4 MB

typedef __attribute__((ext_vector_type(8))) short bf16x8;
typedef __attribute__((ext_vector_type(4))) float f32x4;

__device__ __forceinline__ uint16_t f2bf(float f) {
    union { float f; uint32_t u; } x; x.f = f;
    uint32_t u = x.u;
    uint32_t r = (u + 0x7fffu + ((u >> 16) & 1u)) >> 16;   // RNE
    return (uint16_t)r;
}
__device__ __forceinline__ float b2f_lo(uint32_t v) {
    union { uint32_t u; float f; } x; x.u = v << 16; return x.f;
}
__device__ __forceinline__ float b2f_hi(uint32_t v) {
    union { uint32_t u; float f; } x; x.u = v & 0xffff0000u; return x.f;
}
__device__ __forceinline__ uint32_t pk_bf(float lo, float hi) {
    union { float f; uint32_t u; } a, b; a.f = lo; b.f = hi;
    return ((a.u + 0x8000u) >> 16) | ((b.u + 0x8000u) & 0xffff0000u);
}

// ---------------- prep: weight transposes ----------------
__global__ void k_prep_wa(const float* __restrict__ w_off, uint32_t* __restrict__ wa) {
    int idx = blockIdx.x * 256 + threadIdx.x;              // 9*32*512
    if (idx >= 9 * 32 * 512) return;
    int p = idx / (32 * 512), r = idx % (32 * 512), oc = r / 512, cp = r % 512;
    uint32_t lo = 0, hi = 0;
    if (oc < 27) {
        lo = f2bf(w_off[(size_t)oc * 9216 + (size_t)(cp * 2) * 9 + p]);
        hi = f2bf(w_off[(size_t)oc * 9216 + (size_t)(cp * 2 + 1) * 9 + p]);
    }
    wa[idx] = lo | (hi << 16);
}

// wb[g][p][o][i] bf16 packed: [32][9][32][16] u32
__global__ void k_prep_wb(const float* __restrict__ w_dcn, uint32_t* __restrict__ wb) {
    int idx = blockIdx.x * 256 + threadIdx.x;              // 32*9*32*16
    if (idx >= 32 * 9 * 32 * 16) return;
    int g = idx / (9 * 32 * 16), r = idx % (9 * 32 * 16);
    int p = r / (32 * 16), r2 = r % (32 * 16), o = r2 / 16, ip = r2 % 16;
    uint32_t lo = f2bf(w_dcn[((size_t)(g * 32 + o) * 32 + 2 * ip) * 9 + p]);
    uint32_t hi = f2bf(w_dcn[((size_t)(g * 32 + o) * 32 + 2 * ip + 1) * 9 + p]);
    wb[idx] = lo | (hi << 16);
}

// ---------------- K0: hi_res NCHW f32 -> NHWC bf16 (packed pairs) ----------------
__global__ void k_transpose(const float* __restrict__ x, uint32_t* __restrict__ xt) {
    __shared__ float tile[64][65];
    int cblk = blockIdx.x * 64, y = blockIdx.y, b = blockIdx.z, t = threadIdx.x;
    const float* src = x + ((size_t)(b * 1024 + cblk)) * 4096 + y * 64;
#pragma unroll
    for (int k = 0; k < 16; ++k) {
        int lin = t + k * 256;
        int cl = lin >> 6, xx = lin & 63;
        tile[cl][xx] = src[(size_t)cl * 4096 + xx];
    }
    __syncthreads();
    uint32_t* dst = xt + ((size_t)b * 4096 + y * 64) * 512 + (cblk >> 1);
#pragma unroll
    for (int k = 0; k < 8; ++k) {
        int lin = t + k * 256;
        int xx = lin >> 5, cp = lin & 31;
        uint32_t lo = f2bf(tile[2 * cp][xx]);
        uint32_t hi = f2bf(tile[2 * cp + 1][xx]);
        dst[(size_t)xx * 512 + cp] = lo | (hi << 16);
    }
}

// ---------------- K1: offset conv via MFMA, split by 9 shifts x 2 K-halves ----------------
__global__ __launch_bounds__(256) void k_offconv_mfma(const uint32_t* __restrict__ xt,
                                                      const uint32_t* __restrict__ wa,
                                                      float* __restrict__ part) {
    int sp = blockIdx.x;                       // 0..17: shift p = sp>>1, K-half = sp&1
    int p = sp >> 1, kh = sp & 1;
    int y = blockIdx.y;
    int b = blockIdx.z;
    int t = threadIdx.x;
    int wave = t >> 6, lane = t & 63;
    int col = lane & 15, kg = lane >> 4;
    int x = wave * 16 + col;
    int ky = p / 3 - 1, kx = p % 3 - 1;
    int ys = y + ky, xs = x + kx;
    bool ok = (ys >= 0) && (ys < 64) && (xs >= 0) && (xs < 64);
    int ps = ok ? (ys * 64 + xs) : 0;

    const uint32_t* bp = xt + (size_t)b * 4096 * 512 + (size_t)ps * 512 + kh * 256 + kg * 4;
    const uint32_t* a0 = wa + ((size_t)p * 32 + col) * 512 + kh * 256 + kg * 4;
    const uint32_t* a1 = a0 + 16 * 512;

    f32x4 acc0 = {0.f, 0.f, 0.f, 0.f};
    f32x4 acc1 = {0.f, 0.f, 0.f, 0.f};
#pragma unroll 4
    for (int ks = 0; ks < 16; ++ks) {
        bf16x8 bfrag = {0, 0, 0, 0, 0, 0, 0, 0};
        if (ok) bfrag = *(const bf16x8*)(bp + ks * 16);
        bf16x8 af0 = *(const bf16x8*)(a0 + ks * 16);
        bf16x8 af1 = *(const bf16x8*)(a1 + ks * 16);
        acc0 = __builtin_amdgcn_mfma_f32_16x16x32_bf16(af0, bfrag, acc0, 0, 0, 0);
        acc1 = __builtin_amdgcn_mfma_f32_16x16x32_bf16(af1, bfrag, acc1, 0, 0, 0);
    }
    float* pc = part + ((size_t)(sp * 2 + b)) * 32 * 4096 + (size_t)y * 64 + wave * 16 + col;
#pragma unroll
    for (int j = 0; j < 4; ++j) {
        pc[(size_t)(kg * 4 + j) * 4096]      = acc0[j];
        pc[(size_t)(16 + kg * 4 + j) * 4096] = acc1[j];
    }
}

// ---------------- K2: reduce 18 partials -> sampling meta ----------------
__global__ void k_meta(const float* __restrict__ part, const float* __restrict__ b_off,
                       float4* __restrict__ mw, int4* __restrict__ mi) {
    int idx = blockIdx.x * 256 + threadIdx.x;              // 2*9*4096
    if (idx >= 2 * 9 * 4096) return;
    int b = idx / (9 * 4096), r = idx % (9 * 4096), p = r / 4096, hw = r % 4096;
    int h = hw >> 6, w = hw & 63;
    float sdy = b_off[p], sdx = b_off[p + 9], sm = b_off[p + 18];
#pragma unroll
    for (int s = 0; s < 18; ++s) {
        const float* pb = part + ((size_t)(s * 2 + b)) * 32 * 4096 + hw;
        sdy += pb[(size_t)p * 4096];
        sdx += pb[(size_t)(p + 9) * 4096];
        sm  += pb[(size_t)(p + 18) * 4096];
    }
    float m = 1.f / (1.f + expf(-sm));
    int ky = p / 3 - 1, kx = p % 3 - 1;
    float sy = (float)(h + ky) + sdy;
    float sx = (float)(w + kx) + sdx;
    float y0f = floorf(sy), x0f = floorf(sx);
    float wy = sy - y0f, wx = sx - x0f;
    int y0 = (int)fminf(fmaxf(y0f, -2.f), 64.f);
    int x0 = (int)fminf(fmaxf(x0f, -2.f), 64.f);
    bool vy0 = (y0 >= 0) && (y0 < 64), vy1 = (y0 + 1 >= 0) && (y0 + 1 < 64);
    bool vx0 = (x0 >= 0) && (x0 < 64), vx1 = (x0 + 1 >= 0) && (x0 + 1 < 64);
    float w00 = (1.f - wy) * (1.f - wx) * m * ((vy0 && vx0) ? 1.f : 0.f);
    float w01 = (1.f - wy) * wx         * m * ((vy0 && vx1) ? 1.f : 0.f);
    float w10 = wy * (1.f - wx)         * m * ((vy1 && vx0) ? 1.f : 0.f);
    float w11 = wy * wx                 * m * ((vy1 && vx1) ? 1.f : 0.f);
    int cy0 = min(max(y0, 0), 63),     cx0 = min(max(x0, 0), 63);
    int cy1 = min(max(y0 + 1, 0), 63), cx1 = min(max(x0 + 1, 0), 63);
    mw[idx] = float4{w00, w01, w10, w11};
    mi[idx] = int4{cy0 * 64 + cx0, cy0 * 64 + cx1, cy1 * 64 + cx0, cy1 * 64 + cx1};
}

// ---------------- K3: deformable sample + grouped conv via MFMA (2 px/thread, meta prefetch) ----------------
__global__ __launch_bounds__(256, 4) void k_dcn_mfma(const uint32_t* __restrict__ xt,
                                                     const uint32_t* __restrict__ wb,
                                                     const float4* __restrict__ mw,
                                                     const int4* __restrict__ mi,
                                                     const float* __restrict__ b_dcn,
                                                     float* __restrict__ hial) {
    int g = blockIdx.x, yp = blockIdx.y, b = blockIdx.z;
    int t = threadIdx.x, wave = t >> 6, lane = t & 63;
    int col = lane & 15, kg = lane >> 4;
    int y = yp * 2 + (wave >> 1);
    int xoff = (wave & 1) * 32;
    int pix0 = y * 64 + xoff + col;
    int pix1 = pix0 + 16;

    const uint32_t* xb = xt + (size_t)b * 4096 * 512 + g * 16 + kg * 4;
    const uint32_t* wg = wb + (size_t)g * 9 * 32 * 16 + col * 16 + kg * 4;
    const float4* mwb = mw + (size_t)b * 9 * 4096;
    const int4*   mib = mi + (size_t)b * 9 * 4096;

    f32x4 acc00 = {0.f, 0.f, 0.f, 0.f};   // oc tile 0, pix0
    f32x4 acc10 = {0.f, 0.f, 0.f, 0.f};   // oc tile 1, pix0
    f32x4 acc01 = {0.f, 0.f, 0.f, 0.f};   // oc tile 0, pix1
    f32x4 acc11 = {0.f, 0.f, 0.f, 0.f};   // oc tile 1, pix1

    float4 nw0 = mwb[pix0], nw1 = mwb[pix1];
    int4   ni0 = mib[pix0], ni1 = mib[pix1];
#pragma unroll
    for (int p = 0; p < 9; ++p) {
        float4 w0 = nw0, w1 = nw1;
        int4 i0 = ni0, i1 = ni1;
        if (p < 8) {
            nw0 = mwb[(p + 1) * 4096 + pix0]; nw1 = mwb[(p + 1) * 4096 + pix1];
            ni0 = mib[(p + 1) * 4096 + pix0]; ni1 = mib[(p + 1) * 4096 + pix1];
        }
        uint4 a00 = *(const uint4*)(xb + (size_t)i0.x * 512);
        uint4 a01 = *(const uint4*)(xb + (size_t)i0.y * 512);
        uint4 a10 = *(const uint4*)(xb + (size_t)i0.z * 512);
        uint4 a11 = *(const uint4*)(xb + (size_t)i0.w * 512);
        uint4 c00 = *(const uint4*)(xb + (size_t)i1.x * 512);
        uint4 c01 = *(const uint4*)(xb + (size_t)i1.y * 512);
        uint4 c10 = *(const uint4*)(xb + (size_t)i1.z * 512);
        uint4 c11 = *(const uint4*)(xb + (size_t)i1.w * 512);

        union { uint32_t u[4]; bf16x8 v; } bfr0, bfr1;
#pragma unroll
        for (int e = 0; e < 4; ++e) {
            uint32_t ua = ((const uint32_t*)&a00)[e];
            uint32_t ub = ((const uint32_t*)&a01)[e];
            uint32_t uc = ((const uint32_t*)&a10)[e];
            uint32_t ud = ((const uint32_t*)&a11)[e];
            float lo = w0.x * b2f_lo(ua) + w0.y * b2f_lo(ub) + w0.z * b2f_lo(uc) + w0.w * b2f_lo(ud);
            float hi = w0.x * b2f_hi(ua) + w0.y * b2f_hi(ub) + w0.z * b2f_hi(uc) + w0.w * b2f_hi(ud);
            bfr0.u[e] = pk_bf(lo, hi);
        }
#pragma unroll
        for (int e = 0; e < 4; ++e) {
            uint32_t ua = ((const uint32_t*)&c00)[e];
            uint32_t ub = ((const uint32_t*)&c01)[e];
            uint32_t uc = ((const uint32_t*)&c10)[e];
            uint32_t ud = ((const uint32_t*)&c11)[e];
            float lo = w1.x * b2f_lo(ua) + w1.y * b2f_lo(ub) + w1.z * b2f_lo(uc) + w1.w * b2f_lo(ud);
            float hi = w1.x * b2f_hi(ua) + w1.y * b2f_hi(ub) + w1.z * b2f_hi(uc) + w1.w * b2f_hi(ud);
            bfr1.u[e] = pk_bf(lo, hi);
        }
        const uint32_t* ap = wg + (size_t)p * 32 * 16;
        bf16x8 af0 = *(const bf16x8*)ap;
        bf16x8 af1 = *(const bf16x8*)(ap + 16 * 16);
        acc00 = __builtin_amdgcn_mfma_f32_16x16x32_bf16(af0, bfr0.v, acc00, 0, 0, 0);
        acc10 = __builtin_amdgcn_mfma_f32_16x16x32_bf16(af1, bfr0.v, acc10, 0, 0, 0);
        acc01 = __builtin_amdgcn_mfma_f32_16x16x32_bf16(af0, bfr1.v, acc01, 0, 0, 0);
        acc11 = __builtin_amdgcn_mfma_f32_16x16x32_bf16(af1, bfr1.v, acc11, 0, 0, 0);
    }
    const float* bd = b_dcn + g * 32;
    float* pc0 = hial + ((size_t)b * 1024 + g * 32) * 4096 + pix0;
    float* pc1 = pc0 + 16;
#pragma unroll
    for (int j = 0; j < 4; ++j) {
        float b0 = bd[kg * 4 + j], b1 = bd[16 + kg * 4 + j];
        pc0[(size_t)(kg * 4 + j) * 4096]      = acc00[j] + b0;
        pc0[(size_t)(16 + kg * 4 + j) * 4096] = acc10[j] + b1;
        pc1[(size_t)(kg * 4 + j) * 4096]      = acc01[j] + b0;
        pc1[(size_t)(16 + kg * 4 + j) * 4096] = acc11[j] + b1;
    }
}

// ---------------- K4: fused bilinear 2x upsample + grouped 1x1 conv ----------------
__global__ __launch_bounds__(256) void k_post(const float* __restrict__ lo,
                                              const float* __restrict__ hial,
                                              const float* __restrict__ wp,
                                              const float* __restrict__ bp,
                                              float* __restrict__ out) {
    int gb = blockIdx.x, h = blockIdx.y, b = blockIdx.z, t = threadIdx.x;
    int w = t & 63, gl = t >> 6;
    int g = gb * 4 + gl;
    float fy = 0.5f * h - 0.25f; float fy0 = floorf(fy); float ty = fy - fy0;
    int r0 = (int)fy0; int r1 = r0 + 1; r0 = r0 < 0 ? 0 : r0; r1 = r1 > 31 ? 31 : r1;
    float fx = 0.5f * w - 0.25f; float fx0 = floorf(fx); float tx = fx - fx0;
    int c0 = (int)fx0; int c1 = c0 + 1; c0 = c0 < 0 ? 0 : c0; c1 = c1 > 31 ? 31 : c1;
    float v[12];
    int cbase = g * 12;
#pragma unroll
    for (int i = 0; i < 12; ++i) {
        int c = cbase + i;
        if (c < 2048) {
            const float* lb = lo + ((size_t)(b * 2048 + c)) * 1024;
            float a00 = lb[r0 * 32 + c0], a01 = lb[r0 * 32 + c1];
            float a10 = lb[r1 * 32 + c0], a11 = lb[r1 * 32 + c1];
            v[i] = (1.f - ty) * ((1.f - tx) * a00 + tx * a01)
                 + ty * ((1.f - tx) * a10 + tx * a11);
        } else {
            v[i] = hial[((size_t)b * 1024 + (c - 2048)) * 4096 + h * 64 + w];
        }
    }
    const float* wrow = wp + (size_t)g * 96;
    float* ob_ = out + ((size_t)b * 2048 + g * 8) * 4096 + h * 64 + w;
#pragma unroll
    for (int o = 0; o < 8; ++o) {
        float s = bp[g * 8 + o];
#pragma unroll
        for (int i = 0; i < 12; ++i) s += wrow[o * 12 + i] * v[i];
        ob_[(size_t)o * 4096] = s;
    }
}

extern "C" void kernel_launch(void* const* d_in, const int* in_sizes, int n_in,
                              void* d_out, int out_size, void* d_ws, size_t ws_size,
                              hipStream_t stream) {
    const float* lo_res = (const float*)d_in[0];
    const float* hi_res = (const float*)d_in[1];
    const float* w_off  = (const float*)d_in[2];
    const float* b_off  = (const float*)d_in[3];
    const float* w_dcn  = (const float*)d_in[4];
    const float* b_dcn  = (const float*)d_in[5];
    const float* w_post = (const float*)d_in[6];
    const float* b_post = (const float*)d_in[7];
    float* out = (float*)d_out;
    char* ws = (char*)d_ws;

    uint32_t* xt  = (uint32_t*)(ws + OFF_XT);
    float* hial   = (float*)(ws + OFF_HIAL);
    float* part   = (float*)(ws + OFF_PART);     // aliases hial region (consumed before hial written)
    float4* mwp   = (float4*)(ws + OFF_MW);
    int4* mip     = (int4*)(ws + OFF_MI);
    uint32_t* wa  = (uint32_t*)(ws + OFF_WA);
    uint32_t* wbp = (uint32_t*)(ws + OFF_WB);

    k_prep_wa<<<(9 * 32 * 512 + 255) / 256, 256, 0, stream>>>(w_off, wa);
    k_prep_wb<<<(32 * 9 * 32 * 16 + 255) / 256, 256, 0, stream>>>(w_dcn, wbp);
    k_transpose<<<dim3(16, 64, 2), 256, 0, stream>>>(hi_res, xt);
    k_offconv_mfma<<<dim3(18, 64, 2), 256, 0, stream>>>(xt, wa, part);
    k_meta<<<(2 * 9 * 4096 + 255) / 256, 256, 0, stream>>>(part, b_off, mwp, mip);
    k_dcn_mfma<<<dim3(32, 32, 2), 256, 0, stream>>>(xt, wbp, mwp, mip, b_dcn, hial);
    k_post<<<dim3(64, 64, 2), 256, 0, stream>>>(lo_res, hial, w_post, b_post, out);
}